// Round 3
// baseline (149.130 us; speedup 1.0000x reference)
//
#include <hip/hip_runtime.h>
#include <stdint.h>

#define N_PIX 4096
#define NB 8

typedef __attribute__((ext_vector_type(8))) short short8;
typedef __attribute__((ext_vector_type(4))) float f32x4;
typedef __attribute__((ext_vector_type(16))) float f32x16;

#define SCL 0.18033688011112042f   // log2(e)/8
#define LOG2E 1.4426950408889634f

__device__ __forceinline__ short f2bf(float x){
  union { float f; uint32_t u; } a; a.f = x;
  uint32_t r = a.u + 0x7FFFu + ((a.u >> 16) & 1u);
  return (short)(r >> 16);
}
__device__ __forceinline__ float bf2f(short h){
  union { uint32_t u; float f; } a; a.u = ((uint32_t)(uint16_t)h) << 16; return a.f;
}
__device__ __forceinline__ uint32_t cvtpk(float lo, float hi){
  uint32_t r;
  asm("v_cvt_pk_bf16_f32 %0, %1, %2" : "=v"(r) : "v"(lo), "v"(hi));
  return r;
}
// exchanges: a[lanes 32..63] <-> b[lanes 0..31]
__device__ __forceinline__ void permswap(uint32_t &a, uint32_t &b){
  asm("v_permlane32_swap_b32 %0, %1" : "+v"(a), "+v"(b));
}
__device__ __forceinline__ float fexp2(float x){ return __builtin_amdgcn_exp2f(x); }
__device__ __forceinline__ float wredSum(float v){
  #pragma unroll
  for (int m = 1; m < 64; m <<= 1) v += __shfl_xor(v, m);
  return v;
}
__device__ __forceinline__ float wredMax(float v){
  #pragma unroll
  for (int m = 1; m < 64; m <<= 1) v = fmaxf(v, __shfl_xor(v, m));
  return v;
}

// ---------------- K0a: per-(b,c) spatial mean of x ----------------
__global__ __launch_bounds__(256) void k_xmean(const float* __restrict__ x, float* __restrict__ xm){
  int row = blockIdx.x;            // b*64 + c
  int tid = threadIdx.x;
  const float* xr = x + (size_t)row * N_PIX;
  float s = 0.f;
  #pragma unroll
  for (int i = 0; i < 16; i++) s += xr[tid + 256*i];
  s = wredSum(s);
  __shared__ float red[4];
  if ((tid & 63) == 0) red[tid >> 6] = s;
  __syncthreads();
  if (tid == 0) xm[row] = (red[0]+red[1]+red[2]+red[3]) * (1.0f / N_PIX);
}

// ---------------- K0b: qm = Wq xm + bq, km = Wk xm + bk ----------------
__global__ void k_means(const float* __restrict__ wq, const float* __restrict__ bq,
                        const float* __restrict__ wk, const float* __restrict__ bk,
                        const float* __restrict__ xm, float* __restrict__ qm, float* __restrict__ km){
  int b = blockIdx.x; int c = threadIdx.x;   // 64 threads
  float sq = 0.f, sk = 0.f;
  for (int cc = 0; cc < 64; cc++){
    float xv = xm[b*64 + cc];
    sq += wq[c*64 + cc] * xv;
    sk += wk[c*64 + cc] * xv;
  }
  qm[b*64 + c] = sq + bq[c];
  km[b*64 + c] = sk + bk[c];
}

// ---------------- K1: QKV 1x1-conv GEMM (MFMA) + whitening + unary logits ----------------
// Q: [B][N][64] bf16, whitened & pre-scaled by log2(e)/8
// K: [B][N][64] bf16, whitened (unscaled)
// V: [B][64][N] bf16
// u: [B][N] f32, u[n] = qm . (k[n]-km)
__global__ __launch_bounds__(256) void k_qkv(
    const float* __restrict__ x,
    const float* __restrict__ wq, const float* __restrict__ bq,
    const float* __restrict__ wk, const float* __restrict__ bk,
    const float* __restrict__ wv, const float* __restrict__ bv,
    const float* __restrict__ qm, const float* __restrict__ km,
    short* __restrict__ Q, short* __restrict__ K, short* __restrict__ V,
    float* __restrict__ u)
{
  int blk = blockIdx.x;
  int b  = blk >> 5;
  int n0 = (blk & 31) * 128;
  int tid = threadIdx.x;
  int w = tid >> 6, l = tid & 63, lr = l & 15, lg = l >> 4;
  const float* xb = x + (size_t)b * 64 * N_PIX;

  int ncol[2];
  ncol[0] = n0 + w*32 + lr;
  ncol[1] = ncol[0] + 16;

  // B-fragments from x (shared across the 3 matrices)
  short8 bx[2][2];
  #pragma unroll
  for (int tj = 0; tj < 2; tj++){
    #pragma unroll
    for (int kc = 0; kc < 2; kc++){
      short8 t;
      #pragma unroll
      for (int j = 0; j < 8; j++){
        int cp = kc*32 + lg*8 + j;
        t[j] = f2bf(xb[(size_t)cp * N_PIX + ncol[tj]]);
      }
      bx[tj][kc] = t;
    }
  }

  float qmv[4][4];
  #pragma unroll
  for (int ti = 0; ti < 4; ti++)
    #pragma unroll
    for (int r = 0; r < 4; r++)
      qmv[ti][r] = qm[b*64 + ti*16 + lg*4 + r];

  short* Qb = Q + (size_t)b * N_PIX * 64;
  short* Kb = K + (size_t)b * N_PIX * 64;
  short* Vb = V + (size_t)b * 64 * N_PIX;
  const f32x4 z4 = {0.f, 0.f, 0.f, 0.f};

  // ---------- Q ----------
  {
    short8 aw[4][2];
    #pragma unroll
    for (int ti = 0; ti < 4; ti++)
      #pragma unroll
      for (int kc = 0; kc < 2; kc++){
        const float* wr = wq + (ti*16 + lr)*64 + kc*32 + lg*8;
        short8 t;
        #pragma unroll
        for (int j = 0; j < 8; j++) t[j] = f2bf(wr[j]);
        aw[ti][kc] = t;
      }
    f32x4 acc[4][2];
    #pragma unroll
    for (int ti = 0; ti < 4; ti++)
      #pragma unroll
      for (int tj = 0; tj < 2; tj++){
        acc[ti][tj] = z4;
        #pragma unroll
        for (int kc = 0; kc < 2; kc++)
          acc[ti][tj] = __builtin_amdgcn_mfma_f32_16x16x32_bf16(aw[ti][kc], bx[tj][kc], acc[ti][tj], 0, 0, 0);
      }
    float adj[4][4];
    #pragma unroll
    for (int ti = 0; ti < 4; ti++)
      #pragma unroll
      for (int r = 0; r < 4; r++)
        adj[ti][r] = bq[ti*16 + lg*4 + r] - qmv[ti][r];
    #pragma unroll
    for (int ti = 0; ti < 4; ti++)
      #pragma unroll
      for (int tj = 0; tj < 2; tj++){
        float v0 = (acc[ti][tj][0] + adj[ti][0]) * SCL;
        float v1 = (acc[ti][tj][1] + adj[ti][1]) * SCL;
        float v2 = (acc[ti][tj][2] + adj[ti][2]) * SCL;
        float v3 = (acc[ti][tj][3] + adj[ti][3]) * SCL;
        uint32_t p0 = ((uint32_t)(uint16_t)f2bf(v1) << 16) | (uint16_t)f2bf(v0);
        uint32_t p1 = ((uint32_t)(uint16_t)f2bf(v3) << 16) | (uint16_t)f2bf(v2);
        uint32_t* qr = (uint32_t*)(Qb + (size_t)ncol[tj]*64);
        qr[ti*8 + lg*2]     = p0;
        qr[ti*8 + lg*2 + 1] = p1;
      }
  }

  // ---------- K (+ unary logits) ----------
  {
    short8 aw[4][2];
    #pragma unroll
    for (int ti = 0; ti < 4; ti++)
      #pragma unroll
      for (int kc = 0; kc < 2; kc++){
        const float* wr = wk + (ti*16 + lr)*64 + kc*32 + lg*8;
        short8 t;
        #pragma unroll
        for (int j = 0; j < 8; j++) t[j] = f2bf(wr[j]);
        aw[ti][kc] = t;
      }
    f32x4 acc[4][2];
    #pragma unroll
    for (int ti = 0; ti < 4; ti++)
      #pragma unroll
      for (int tj = 0; tj < 2; tj++){
        acc[ti][tj] = z4;
        #pragma unroll
        for (int kc = 0; kc < 2; kc++)
          acc[ti][tj] = __builtin_amdgcn_mfma_f32_16x16x32_bf16(aw[ti][kc], bx[tj][kc], acc[ti][tj], 0, 0, 0);
      }
    float adj[4][4];
    #pragma unroll
    for (int ti = 0; ti < 4; ti++)
      #pragma unroll
      for (int r = 0; r < 4; r++)
        adj[ti][r] = bk[ti*16 + lg*4 + r] - km[b*64 + ti*16 + lg*4 + r];
    float up[2] = {0.f, 0.f};
    #pragma unroll
    for (int ti = 0; ti < 4; ti++)
      #pragma unroll
      for (int tj = 0; tj < 2; tj++){
        float v0 = acc[ti][tj][0] + adj[ti][0];
        float v1 = acc[ti][tj][1] + adj[ti][1];
        float v2 = acc[ti][tj][2] + adj[ti][2];
        float v3 = acc[ti][tj][3] + adj[ti][3];
        up[tj] += qmv[ti][0]*v0 + qmv[ti][1]*v1 + qmv[ti][2]*v2 + qmv[ti][3]*v3;
        uint32_t p0 = ((uint32_t)(uint16_t)f2bf(v1) << 16) | (uint16_t)f2bf(v0);
        uint32_t p1 = ((uint32_t)(uint16_t)f2bf(v3) << 16) | (uint16_t)f2bf(v2);
        uint32_t* kr = (uint32_t*)(Kb + (size_t)ncol[tj]*64);
        kr[ti*8 + lg*2]     = p0;
        kr[ti*8 + lg*2 + 1] = p1;
      }
    #pragma unroll
    for (int tj = 0; tj < 2; tj++){
      float s = up[tj];
      s += __shfl_xor(s, 16);
      s += __shfl_xor(s, 32);
      if (lg == 0) u[(size_t)b*N_PIX + ncol[tj]] = s;
    }
  }

  // ---------- V ----------
  {
    short8 aw[4][2];
    #pragma unroll
    for (int ti = 0; ti < 4; ti++)
      #pragma unroll
      for (int kc = 0; kc < 2; kc++){
        const float* wr = wv + (ti*16 + lr)*64 + kc*32 + lg*8;
        short8 t;
        #pragma unroll
        for (int j = 0; j < 8; j++) t[j] = f2bf(wr[j]);
        aw[ti][kc] = t;
      }
    f32x4 acc[4][2];
    #pragma unroll
    for (int ti = 0; ti < 4; ti++)
      #pragma unroll
      for (int tj = 0; tj < 2; tj++){
        acc[ti][tj] = z4;
        #pragma unroll
        for (int kc = 0; kc < 2; kc++)
          acc[ti][tj] = __builtin_amdgcn_mfma_f32_16x16x32_bf16(aw[ti][kc], bx[tj][kc], acc[ti][tj], 0, 0, 0);
      }
    #pragma unroll
    for (int ti = 0; ti < 4; ti++)
      #pragma unroll
      for (int tj = 0; tj < 2; tj++){
        #pragma unroll
        for (int r = 0; r < 4; r++){
          float v = acc[ti][tj][r] + bv[ti*16 + lg*4 + r];
          Vb[(size_t)(ti*16 + lg*4 + r) * N_PIX + ncol[tj]] = f2bf(v);
        }
      }
  }
}

// ---------------- K2: unary softmax + out_unary ----------------
__global__ __launch_bounds__(256) void k_unary(const float* __restrict__ u, const short* __restrict__ V,
                                               float* __restrict__ ou){
  int b = blockIdx.x >> 6, c = blockIdx.x & 63;
  int tid = threadIdx.x, w = tid >> 6, l = tid & 63;
  const float* ub = u + (size_t)b * N_PIX;
  float mx = -1e30f;
  #pragma unroll
  for (int i = 0; i < 16; i++) mx = fmaxf(mx, ub[tid + 256*i]);
  mx = wredMax(mx);
  __shared__ float redm[4];
  if (l == 0) redm[w] = mx;
  __syncthreads();
  mx = fmaxf(fmaxf(redm[0], redm[1]), fmaxf(redm[2], redm[3]));
  const short* Vr = V + ((size_t)b*64 + c) * N_PIX;
  float ps = 0.f, vs = 0.f;
  #pragma unroll
  for (int i = 0; i < 16; i++){
    int m = tid + 256*i;
    float p = exp2f((ub[m] - mx) * LOG2E);
    ps += p;
    vs += p * bf2f(Vr[m]);
  }
  ps = wredSum(ps); vs = wredSum(vs);
  __shared__ float r1[4], r2[4];
  if (l == 0){ r1[w] = ps; r2[w] = vs; }
  __syncthreads();
  if (tid == 0) ou[b*64 + c] = (r2[0]+r2[1]+r2[2]+r2[3]) / (r1[0]+r1[1]+r1[2]+r1[3]);
}

// ---------------- K3: flash attention + epilogue (32x32 MFMA, in-register P) ----------------
// 512 threads = 8 waves: wave w = (qh = w&1, kq = w>>2? no: kq = w>>1).
// Wave handles q-rows [q0 + qh*32, +32), keys [kq*1024, +1024) in 32-key steps.
// Swapped QK^T: S^T = mfma_32x32x16(K, Q): lane(q=l&31, hi=l>>5) holds 16 keys
// rows {0..3,8..11,16..19,24..27}+4hi. P redistributed to PV A-frag layout via
// cvt_pk + permlane32_swap — no LDS in the loop.
__global__ __launch_bounds__(512, 3) void k_attn(
    const short* __restrict__ Q, const short* __restrict__ K, const short* __restrict__ V,
    const float* __restrict__ ou, const float* __restrict__ x, float* __restrict__ out)
{
  int b  = blockIdx.x >> 6;
  int q0 = (blockIdx.x & 63) << 6;
  int tid = threadIdx.x;
  int w = tid >> 6;            // 0..7
  int l = tid & 63;
  int l31 = l & 31, hi = l >> 5;
  int qh = w & 1, kq = w >> 1;

  __shared__ short Opart[8][32][66];   // [wave][q_local][c] bf16 partials
  __shared__ float lW[8][32];          // [wave][q_local] partial row sums

  const short* Qb = Q + (size_t)b * N_PIX * 64;
  const short* Kb = K + (size_t)b * N_PIX * 64;
  const short* Vb = V + (size_t)b * 64 * N_PIX;

  // Q B-fragments: lane(q=l31, hi): channels m*16 + hi*8 + j
  short8 qf[4];
  #pragma unroll
  for (int m = 0; m < 4; m++)
    qf[m] = *(const short8*)(Qb + (size_t)(q0 + qh*32 + l31)*64 + m*16 + hi*8);

  f32x16 accA, accB;
  #pragma unroll
  for (int r = 0; r < 16; r++){ accA[r] = 0.f; accB[r] = 0.f; }
  float rs = 0.f;

  int kbase = kq << 10;
  for (int it = 0; it < 32; ++it){
    int kb = kbase + (it << 5);
    // K A-frags: lane row = key kb+l31, channels m*16 + hi*8 + j
    const short* kp = Kb + (size_t)(kb + l31)*64 + hi*8;
    short8 ak0 = *(const short8*)(kp);
    short8 ak1 = *(const short8*)(kp + 16);
    short8 ak2 = *(const short8*)(kp + 32);
    short8 ak3 = *(const short8*)(kp + 48);
    // V B-frags: lane col = c(half)+l31, keys kb + kh*16 + hi*8 + j
    const short* vp = Vb + (size_t)l31 * N_PIX + kb + hi*8;
    short8 av00 = *(const short8*)(vp);                        // c 0..31, keys lo16
    short8 av01 = *(const short8*)(vp + 16);                   // c 0..31, keys hi16
    short8 av10 = *(const short8*)(vp + (size_t)32*N_PIX);     // c 32..63, keys lo16
    short8 av11 = *(const short8*)(vp + (size_t)32*N_PIX + 16);

    f32x16 st;
    #pragma unroll
    for (int r = 0; r < 16; r++) st[r] = 0.f;
    st = __builtin_amdgcn_mfma_f32_32x32x16_bf16(ak0, qf[0], st, 0, 0, 0);
    st = __builtin_amdgcn_mfma_f32_32x32x16_bf16(ak1, qf[1], st, 0, 0, 0);
    st = __builtin_amdgcn_mfma_f32_32x32x16_bf16(ak2, qf[2], st, 0, 0, 0);
    st = __builtin_amdgcn_mfma_f32_32x32x16_bf16(ak3, qf[3], st, 0, 0, 0);

    // ---- softmax + redistribute, keys 0..15 (regs 0..7) ----
    {
      float p0 = fexp2(st[0]), p1 = fexp2(st[1]), p2 = fexp2(st[2]), p3 = fexp2(st[3]);
      float p4 = fexp2(st[4]), p5 = fexp2(st[5]), p6 = fexp2(st[6]), p7 = fexp2(st[7]);
      rs += ((p0+p1)+(p2+p3)) + ((p4+p5)+(p6+p7));
      uint32_t a0 = cvtpk(p0, p1), a1 = cvtpk(p2, p3);
      uint32_t b0 = cvtpk(p4, p5), b1 = cvtpk(p6, p7);
      permswap(a0, b0);   // a0: j0,1  b0: j4,5
      permswap(a1, b1);   // a1: j2,3  b1: j6,7
      union { short8 s; uint32_t u[4]; } pa;
      pa.u[0] = a0; pa.u[1] = a1; pa.u[2] = b0; pa.u[3] = b1;
      accA = __builtin_amdgcn_mfma_f32_32x32x16_bf16(pa.s, av00, accA, 0, 0, 0);
      accB = __builtin_amdgcn_mfma_f32_32x32x16_bf16(pa.s, av10, accB, 0, 0, 0);
    }
    // ---- softmax + redistribute, keys 16..31 (regs 8..15) ----
    {
      float p0 = fexp2(st[8]),  p1 = fexp2(st[9]),  p2 = fexp2(st[10]), p3 = fexp2(st[11]);
      float p4 = fexp2(st[12]), p5 = fexp2(st[13]), p6 = fexp2(st[14]), p7 = fexp2(st[15]);
      rs += ((p0+p1)+(p2+p3)) + ((p4+p5)+(p6+p7));
      uint32_t a0 = cvtpk(p0, p1), a1 = cvtpk(p2, p3);
      uint32_t b0 = cvtpk(p4, p5), b1 = cvtpk(p6, p7);
      permswap(a0, b0);
      permswap(a1, b1);
      union { short8 s; uint32_t u[4]; } pb;
      pb.u[0] = a0; pb.u[1] = a1; pb.u[2] = b0; pb.u[3] = b1;
      accA = __builtin_amdgcn_mfma_f32_32x32x16_bf16(pb.s, av01, accA, 0, 0, 0);
      accB = __builtin_amdgcn_mfma_f32_32x32x16_bf16(pb.s, av11, accB, 0, 0, 0);
    }
  }

  // rs: lane(q,hi) has sum over its half of keys; combine hi halves
  rs += __shfl_xor(rs, 32);
  if (hi == 0) lW[w][l31] = rs;

  #pragma unroll
  for (int r = 0; r < 16; r++){
    int row = (r & 3) + 8*(r >> 2) + 4*hi;
    Opart[w][row][l31]      = f2bf(accA[r]);
    Opart[w][row][32 + l31] = f2bf(accB[r]);
  }
  __syncthreads();

  const float* xb = x + (size_t)b * 64 * N_PIX;
  float* ob = out + (size_t)b * 64 * N_PIX;
  #pragma unroll
  for (int i = 0; i < 8; i++){
    int idx = i*512 + tid;
    int c = idx >> 6, q = idx & 63;
    int qhh = q >> 5, ql = q & 31;
    float os = bf2f(Opart[qhh][ql][c]) + bf2f(Opart[qhh+2][ql][c])
             + bf2f(Opart[qhh+4][ql][c]) + bf2f(Opart[qhh+6][ql][c]);
    float lt = lW[qhh][ql] + lW[qhh+2][ql] + lW[qhh+4][ql] + lW[qhh+6][ql];
    size_t gi = (size_t)c * N_PIX + q0 + q;
    ob[gi] = xb[gi] + os / lt + ou[b*64 + c];
  }
}

extern "C" void kernel_launch(void* const* d_in, const int* in_sizes, int n_in,
                              void* d_out, int out_size, void* d_ws, size_t ws_size,
                              hipStream_t stream)
{
  (void)in_sizes; (void)n_in; (void)out_size; (void)ws_size;
  const float* x  = (const float*)d_in[0];
  const float* wq = (const float*)d_in[1];
  const float* bq = (const float*)d_in[2];
  const float* wk = (const float*)d_in[3];
  const float* bk = (const float*)d_in[4];
  const float* wv = (const float*)d_in[5];
  const float* bv = (const float*)d_in[6];
  float* out = (float*)d_out;

  char* ws = (char*)d_ws;
  short* Q  = (short*)(ws);                 // 8*4096*64 bf16 = 4 MiB
  short* K  = (short*)(ws + 4194304);       // 4 MiB
  short* V  = (short*)(ws + 8388608);       // 4 MiB
  float* u  = (float*)(ws + 12582912);      // 8*4096 f32 = 128 KiB
  float* xm = (float*)(ws + 12713984);      // 8*64 f32
  float* qm = (float*)(ws + 12716032);
  float* km = (float*)(ws + 12718080);
  float* ou = (float*)(ws + 12720128);

  k_xmean<<<dim3(512), dim3(256), 0, stream>>>(x, xm);
  k_means<<<dim3(8), dim3(64), 0, stream>>>(wq, bq, wk, bk, xm, qm, km);
  k_qkv<<<dim3(256), dim3(256), 0, stream>>>(x, wq, bq, wk, bk, wv, bv, qm, km, Q, K, V, u);
  k_unary<<<dim3(512), dim3(256), 0, stream>>>(u, V, ou);
  k_attn<<<dim3(512), dim3(512), 0, stream>>>(Q, K, V, ou, x, out);
}